// Round 4
// baseline (154.683 us; speedup 1.0000x reference)
//
#include <hip/hip_runtime.h>
#include <hip/hip_bf16.h>

// Problem constants: B=2, T=4096, E=512, H=8, D=64
#define T_SEQ 4096
#define EMB   512
#define NH    8
#define HD    64
#define BATCH 2
#define M_ROWS (BATCH * T_SEQ)   // 8192
#define NCHUNK 64                // T / CS
#define CS     64                // chunk size
#define BHEADS (BATCH * NH)      // 16

using bf16 = __hip_bfloat16;
typedef __attribute__((ext_vector_type(8))) short short8;   // 8 bf16 = 4 VGPR
typedef __attribute__((ext_vector_type(4))) float floatx4;  // MFMA acc

__device__ __forceinline__ float bs2f(short s) {
    return __uint_as_float(((unsigned)(unsigned short)s) << 16);
}
__device__ __forceinline__ short f2bs(float f) {
    bf16 h = __float2bfloat16(f);
    return *reinterpret_cast<short*>(&h);
}
__device__ __forceinline__ float load_elem(const bf16* p, size_t i) {
    return __bfloat162float(p[i]);
}
// convert 8 consecutive elems (any dtype) -> bf16, 16B write
__device__ __forceinline__ void stage8(const bf16* g, short* l) {
    *reinterpret_cast<short8*>(l) = *reinterpret_cast<const short8*>(g);
}
__device__ __forceinline__ void stage8(const float* g, short* l) {
    float4 a = *reinterpret_cast<const float4*>(g);
    float4 b = *reinterpret_cast<const float4*>(g + 4);
    short8 v;
    v[0] = f2bs(a.x); v[1] = f2bs(a.y); v[2] = f2bs(a.z); v[3] = f2bs(a.w);
    v[4] = f2bs(b.x); v[5] = f2bs(b.y); v[6] = f2bs(b.z); v[7] = f2bs(b.w);
    *reinterpret_cast<short8*>(l) = v;
}

// async global->LDS: each lane copies 16B to (wave-uniform base) + lane*16
__device__ __forceinline__ void gload_lds16(const short* g, short* l) {
    __builtin_amdgcn_global_load_lds(
        (const __attribute__((address_space(1))) void*)g,
        (__attribute__((address_space(3))) void*)l, 16, 0, 0);
}

#define LDSTR 72   // padded LDS row stride (shorts) for transposed tiles

// ---------------------------------------------------------------------------
// In-block dtype probe (validated).  Requires 256+ threads; uses tid&255.
// ---------------------------------------------------------------------------
__device__ __forceinline__ int probe_mode(const void* x) {
    const uint4* p = (const uint4*)x;
    const int tid = threadIdx.x & 255;
    bool bad = false;
    #pragma unroll
    for (int i = 0; i < 2; ++i) {
        uint4 u = p[tid + i * 256];
        const unsigned w[4] = {u.x, u.y, u.z, u.w};
        #pragma unroll
        for (int k = 0; k < 4; ++k) {
            const float f = __uint_as_float(w[k] << 16);   // low half (even short)
            if (!(fabsf(f) <= 1e9f)) bad = true;
        }
    }
    return __syncthreads_or(bad ? 1 : 0) ? 1 : 0;
}

// ---------------------------------------------------------------------------
// Kernel 1: convert x, Wq/Wk/Wv/Wo, biases -> bf16 workspace (self-probing).
// ---------------------------------------------------------------------------
template <typename T>
__device__ __forceinline__ void convert_body(
    const void* const* in, short* xb, short* Wb, short* bb, int c)
{
    if (c < 524288) {
        stage8((const T*)in[0] + (size_t)c * 8, xb + (size_t)c * 8);
    } else if (c < 655360) {
        const int c2 = c - 524288;
        const int w = c2 >> 15;             // 0..3 : Wq Wk Wv Wo
        const int off = (c2 & 32767) * 8;
        const T* src = (const T*)in[w == 0 ? 1 : (w == 1 ? 3 : (w == 2 ? 5 : 7))];
        stage8(src + off, Wb + w * 262144 + off);
    } else if (c < 655616) {
        const int c3 = c - 655360;          // 0..255
        const int bsel = c3 >> 6;
        const int off = (c3 & 63) * 8;
        const T* src = (const T*)in[bsel == 0 ? 2 : (bsel == 1 ? 4 : (bsel == 2 ? 6 : 8))];
        stage8(src + off, bb + bsel * 512 + off);
    }
}

__global__ __launch_bounds__(256) void convert_all(
    const void* x, const void* Wq, const void* bq,
    const void* Wk, const void* bk, const void* Wv, const void* bv,
    const void* Wo, const void* bo,
    short* __restrict__ xb, short* __restrict__ Wb, short* __restrict__ bb)
{
    const void* in[9] = {x, Wq, bq, Wk, bk, Wv, bv, Wo, bo};
    const int mode = probe_mode(x);
    const int c = blockIdx.x * 256 + threadIdx.x;
    if (mode) convert_body<float>(in, xb, Wb, bb, c);
    else      convert_body<bf16>(in, xb, Wb, bb, c);
}

// ---------------------------------------------------------------------------
// Kernel 2: fused QKV projection — 256x192 tile, FULL double-buffer, one
// barrier per K-step (2-phase pipeline).  Grid (32,8) = 256 blocks = exactly
// 1/CU, even distribution.  N=192 tiles span the contiguous [Wq;Wk;Wv] rows
// of Wb; epilogue resolves which/elu per column.  LDS 112KB.
// ---------------------------------------------------------------------------
__global__ __launch_bounds__(512) void qkv_gemm_dl(
    const short* __restrict__ xb, const short* __restrict__ Wb,
    const short* __restrict__ bb,
    bf16* __restrict__ Qf, bf16* __restrict__ Kf, bf16* __restrict__ Vf)
{
    const int mbase = blockIdx.x * 256;      // 0..31
    const int nbase = blockIdx.y * 192;      // 0..7 -> cols 0..1535

    __shared__ short As[2][256 * 64];   // 32KB x2
    __shared__ short Bs[2][192 * 64];   // 24KB x2

    const int tid  = threadIdx.x;
    const int wave = tid >> 6, lane = tid & 63;   // 8 waves
    const int wm = wave >> 1, wn = wave & 1;      // 4M x 2N over 256x192
    const int lm = lane & 15, quad = lane >> 4;
    const int srow = lane >> 3;           // 0..7 within issue
    const int scol = (lane & 7) * 8;      // 0,8,..,56

    floatx4 acc[4][6];
    const floatx4 zero = {0.f, 0.f, 0.f, 0.f};
    #pragma unroll
    for (int mt = 0; mt < 4; ++mt)
        #pragma unroll
        for (int nt = 0; nt < 6; ++nt) acc[mt][nt] = zero;

    // stage one K-step (64 cols) of A(256 rows) + B(192 rows) into buffer buf
    auto stage = [&](int buf, int kt) {
        #pragma unroll
        for (int j = 0; j < 4; ++j) {                 // A: 32 issues x 8 rows
            const int issue = wave * 4 + j;           // 0..31
            const int row = issue * 8 + srow;         // 0..255
            gload_lds16(xb + (size_t)(mbase + row) * EMB + kt + scol,
                        &As[buf][issue * 512]);
        }
        #pragma unroll
        for (int j = 0; j < 3; ++j) {                 // B: 24 issues x 8 rows
            const int issue = wave * 3 + j;           // 0..23
            const int row = issue * 8 + srow;         // 0..191
            gload_lds16(Wb + (size_t)(nbase + row) * EMB + kt + scol,
                        &Bs[buf][issue * 512]);
        }
    };

    stage(0, 0);
    __syncthreads();

    #pragma unroll 2
    for (int step = 0; step < 8; ++step) {
        const int cur = step & 1;
        if (step < 7) stage(cur ^ 1, (step + 1) * 64);   // async, flies under MFMA
        #pragma unroll
        for (int ks = 0; ks < 2; ++ks) {
            short8 af[4], bfr[6];
            #pragma unroll
            for (int mt = 0; mt < 4; ++mt)
                af[mt] = *reinterpret_cast<const short8*>(
                    &As[cur][(wm * 64 + mt * 16 + lm) * 64 + ks * 32 + quad * 8]);
            #pragma unroll
            for (int nt = 0; nt < 6; ++nt)
                bfr[nt] = *reinterpret_cast<const short8*>(
                    &Bs[cur][(wn * 96 + nt * 16 + lm) * 64 + ks * 32 + quad * 8]);
            #pragma unroll
            for (int mt = 0; mt < 4; ++mt)
                #pragma unroll
                for (int nt = 0; nt < 6; ++nt)
                    acc[mt][nt] = __builtin_amdgcn_mfma_f32_16x16x32_bf16(
                        af[mt], bfr[nt], acc[mt][nt], 0, 0, 0);
        }
        if (step < 7) __syncthreads();   // drains staging; protects buffer reuse
    }

    #pragma unroll
    for (int nt = 0; nt < 6; ++nt) {
        const int col = nbase + wn * 96 + nt * 16 + lm;   // 0..1535
        const int which = col >> 9;                        // 0=Q 1=K 2=V
        const int cw = col & 511;
        const float bv_ = load_elem((const bf16*)bb, col); // bb: 4x512, Q/K/V first
        const int h = cw >> 6, d = cw & 63;
        bf16* outp = (which == 0) ? Qf : ((which == 1) ? Kf : Vf);
        #pragma unroll
        for (int mt = 0; mt < 4; ++mt)
            #pragma unroll
            for (int r = 0; r < 4; ++r) {
                const int row = mbase + wm * 64 + mt * 16 + quad * 4 + r;
                const int b = row >> 12, t = row & (T_SEQ - 1);
                float v = acc[mt][nt][r] + bv_;
                if (which != 2) v = (v > 0.f) ? (v + 1.f) : __expf(v);  // elu+1
                outp[(((size_t)(b * NH + h)) * T_SEQ + t) * HD + d] = __float2bfloat16(v);
            }
    }
}

// ---------------------------------------------------------------------------
// Kernel 3: per-chunk (K^T V)^T via MFMA + k column sums.  1024 blocks.
// ---------------------------------------------------------------------------
__global__ __launch_bounds__(256) void chunk_kv(
    const bf16* __restrict__ Kf, const bf16* __restrict__ Vf,
    float* __restrict__ KVt, float* __restrict__ ksum)
{
    const int bh = blockIdx.x >> 6;
    const int c  = blockIdx.x & 63;
    __shared__ short Kt[64 * LDSTR];   // Kt[dk][s]
    __shared__ short Vt[64 * LDSTR];   // Vt[dv][s]
    const int tid = threadIdx.x;
    const bf16* kp = Kf + ((size_t)bh * T_SEQ + c * CS) * HD;
    const bf16* vp = Vf + ((size_t)bh * T_SEQ + c * CS) * HD;

    #pragma unroll
    for (int j = 0; j < 2; ++j) {
        const int u = j * 256 + tid;
        const int e0 = u * 8;
        const int s = e0 >> 6, d0 = e0 & 63;
        short8 ku = *reinterpret_cast<const short8*>(kp + e0);
        short8 vu = *reinterpret_cast<const short8*>(vp + e0);
        #pragma unroll
        for (int i = 0; i < 8; ++i) {
            Kt[(d0 + i) * LDSTR + s] = ku[i];
            Vt[(d0 + i) * LDSTR + s] = vu[i];
        }
    }
    __syncthreads();

    const int w = tid >> 6, lane = tid & 63;
    const int lm = lane & 15, quad = lane >> 4;

    floatx4 acc[4];
    const floatx4 zero = {0.f, 0.f, 0.f, 0.f};
    #pragma unroll
    for (int nt = 0; nt < 4; ++nt) acc[nt] = zero;

    #pragma unroll
    for (int ks = 0; ks < 2; ++ks) {
        short8 av = *reinterpret_cast<const short8*>(
            &Vt[(w * 16 + lm) * LDSTR + ks * 32 + quad * 8]);   // A: rows = dv
        #pragma unroll
        for (int nt = 0; nt < 4; ++nt) {
            short8 bk = *reinterpret_cast<const short8*>(
                &Kt[(nt * 16 + lm) * LDSTR + ks * 32 + quad * 8]);  // B: cols = dk
            acc[nt] = __builtin_amdgcn_mfma_f32_16x16x32_bf16(av, bk, acc[nt], 0, 0, 0);
        }
    }

    float* kvout = KVt + ((size_t)bh * NCHUNK + c) * 4096;
    #pragma unroll
    for (int nt = 0; nt < 4; ++nt)
        #pragma unroll
        for (int r = 0; r < 4; ++r)
            kvout[(w * 16 + quad * 4 + r) * 64 + nt * 16 + lm] = acc[nt][r];

    if (tid < 64) {
        float s = 0.f;
        #pragma unroll 8
        for (int t = 0; t < 64; ++t) s += bs2f(Kt[tid * LDSTR + t]);
        ksum[((size_t)bh * NCHUNK + c) * 64 + tid] = s;
    }
}

// ---------------------------------------------------------------------------
// Kernel 4: exclusive prefix over chunks — element-parallel.  fp32 scan
// internally, bf16 output (attn rounds to bf16 anyway -> bit-identical).
// ---------------------------------------------------------------------------
__global__ __launch_bounds__(256) void prefix_kv(
    const float* __restrict__ KVt, bf16* __restrict__ KVb,
    float* __restrict__ ksum)
{
    const int bh   = blockIdx.x >> 4;
    const int part = blockIdx.x & 15;
    const int tid  = threadIdx.x;
    const int e    = part * 256 + tid;
    const float* src = KVt + (size_t)bh * NCHUNK * 4096 + e;
    bf16* dst = KVb + (size_t)bh * NCHUNK * 4096 + e;

    float s = 0.f;
    #pragma unroll
    for (int cb = 0; cb < 2; ++cb) {
        float v[32];
        #pragma unroll
        for (int i = 0; i < 32; ++i) v[i] = src[(size_t)(cb * 32 + i) * 4096];
        #pragma unroll
        for (int i = 0; i < 32; ++i) {
            dst[(size_t)(cb * 32 + i) * 4096] = __float2bfloat16(s);
            s += v[i];
        }
    }

    if (part == 0 && tid < 64) {
        float* zb = ksum + (size_t)bh * NCHUNK * 64 + tid;
        float z = 0.f;
        #pragma unroll
        for (int cb = 0; cb < 4; ++cb) {
            float zv[16];
            #pragma unroll
            for (int i = 0; i < 16; ++i) zv[i] = zb[(size_t)(cb * 16 + i) * 64];
            #pragma unroll
            for (int i = 0; i < 16; ++i) {
                zb[(size_t)(cb * 16 + i) * 64] = z;
                z += zv[i];
            }
        }
    }
}

// ---------------------------------------------------------------------------
// Kernel 5: per-chunk attention, all-MFMA, registerized denominator.
// 4 blocks/CU (37.25KB LDS), single occupancy wave.
// ---------------------------------------------------------------------------
__global__ __launch_bounds__(256, 4) void attn_mfma(
    const bf16* __restrict__ Qf, const bf16* __restrict__ Kf,
    const bf16* __restrict__ Vf, const bf16* __restrict__ KVb,
    const float* __restrict__ ksum, bf16* __restrict__ Of)
{
    const int bh = blockIdx.x >> 6;
    const int c  = blockIdx.x & 63;
    const int b  = bh >> 3, h = bh & 7;

    __shared__ short Qs [64 * LDSTR];
    __shared__ short Ksn[64 * LDSTR];
    __shared__ short Vt [64 * LDSTR];
    __shared__ short Ps [64 * LDSTR];
    __shared__ float zprev[64];

    const int tid = threadIdx.x;
    const int w = tid >> 6, lane = tid & 63;
    const int lm = lane & 15, quad = lane >> 4;
    const size_t coff = ((size_t)bh * T_SEQ + c * CS) * HD;
    const bf16* Sb = KVb + ((size_t)bh * NCHUNK + c) * 4096;

    #pragma unroll
    for (int j = 0; j < 2; ++j) {
        const int u  = j * 256 + tid;
        const int e0 = u * 8;
        const int r = e0 >> 6, cc = e0 & 63;
        *reinterpret_cast<short8*>(&Qs [r * LDSTR + cc]) =
            *reinterpret_cast<const short8*>(Qf + coff + e0);
        *reinterpret_cast<short8*>(&Ksn[r * LDSTR + cc]) =
            *reinterpret_cast<const short8*>(Kf + coff + e0);
        short8 vu = *reinterpret_cast<const short8*>(Vf + coff + e0);
        #pragma unroll
        for (int i = 0; i < 8; ++i) Vt[(cc + i) * LDSTR + r] = vu[i];
    }
    if (tid < 64) zprev[tid] = ksum[((size_t)bh * NCHUNK + c) * 64 + tid];
    __syncthreads();

    const floatx4 zero = {0.f, 0.f, 0.f, 0.f};
    short8 aq[2];
    #pragma unroll
    for (int ks = 0; ks < 2; ++ks)
        aq[ks] = *reinterpret_cast<const short8*>(
            &Qs[(w * 16 + lm) * LDSTR + ks * 32 + quad * 8]);

    floatx4 pacc[4];
    #pragma unroll
    for (int nt = 0; nt < 4; ++nt) pacc[nt] = zero;
    #pragma unroll
    for (int ks = 0; ks < 2; ++ks)
        #pragma unroll
        for (int nt = 0; nt < 4; ++nt) {
            short8 bk = *reinterpret_cast<const short8*>(
                &Ksn[(nt * 16 + lm) * LDSTR + ks * 32 + quad * 8]);
            pacc[nt] = __builtin_amdgcn_mfma_f32_16x16x32_bf16(aq[ks], bk, pacc[nt], 0, 0, 0);
        }

    float tot[4] = {0.f, 0.f, 0.f, 0.f};
    #pragma unroll
    for (int nt = 0; nt < 4; ++nt)
        #pragma unroll
        for (int r = 0; r < 4; ++r) {
            const int t = w * 16 + quad * 4 + r;
            const int s = nt * 16 + lm;
            const float m = (s <= t) ? pacc[nt][r] : 0.f;
            Ps[t * LDSTR + s] = f2bs(m);
            tot[r] += m;
        }
    #pragma unroll
    for (int r = 0; r < 4; ++r) {
        const int t = w * 16 + quad * 4 + r;
        #pragma unroll
        for (int j = 0; j < 4; ++j) {
            const int d = lm + j * 16;
            tot[r] += bs2f(Qs[t * LDSTR + d]) * zprev[d];
        }
    }
    #pragma unroll
    for (int mask = 1; mask < 16; mask <<= 1)
        #pragma unroll
        for (int r = 0; r < 4; ++r) tot[r] += __shfl_xor(tot[r], mask);
    float rdenl[4];
    #pragma unroll
    for (int r = 0; r < 4; ++r) rdenl[r] = 1.f / (tot[r] + 1e-6f);

    floatx4 oacc[4];
    #pragma unroll
    for (int nt = 0; nt < 4; ++nt) oacc[nt] = zero;
    #pragma unroll
    for (int ks = 0; ks < 2; ++ks)
        #pragma unroll
        for (int nt = 0; nt < 4; ++nt) {
            short8 bs = *reinterpret_cast<const short8*>(
                Sb + (nt * 16 + lm) * 64 + ks * 32 + quad * 8);
            oacc[nt] = __builtin_amdgcn_mfma_f32_16x16x32_bf16(aq[ks], bs, oacc[nt], 0, 0, 0);
        }

    #pragma unroll
    for (int ks = 0; ks < 2; ++ks) {
        short8 ap = *reinterpret_cast<const short8*>(
            &Ps[(w * 16 + lm) * LDSTR + ks * 32 + quad * 8]);
        #pragma unroll
        for (int nt = 0; nt < 4; ++nt) {
            short8 bv = *reinterpret_cast<const short8*>(
                &Vt[(nt * 16 + lm) * LDSTR + ks * 32 + quad * 8]);
            oacc[nt] = __builtin_amdgcn_mfma_f32_16x16x32_bf16(ap, bv, oacc[nt], 0, 0, 0);
        }
    }

    #pragma unroll
    for (int nt = 0; nt < 4; ++nt)
        #pragma unroll
        for (int r = 0; r < 4; ++r) {
            const int t  = w * 16 + quad * 4 + r;
            const int dv = nt * 16 + lm;
            const int tg = c * CS + t;
            Of[((size_t)(b * T_SEQ + tg)) * EMB + h * HD + dv] =
                __float2bfloat16(oacc[nt][r] * rdenl[r]);
        }
}

// ---------------------------------------------------------------------------
// Kernel 6: output projection — 128x128 tile with FULL double-buffer,
// one barrier per K-step.  Grid (64,4) = 256 blocks = 1/CU.  LDS 64KB.
// ---------------------------------------------------------------------------
__global__ __launch_bounds__(256) void out_proj_dl(
    const void* __restrict__ xprobe,
    const short* __restrict__ A, const short* __restrict__ Wb,
    const short* __restrict__ bb, void* __restrict__ out)
{
    const int mode = probe_mode(xprobe);

    const int mbase = blockIdx.x * 128;
    const int nbase = blockIdx.y * 128;
    const short* W = Wb + (size_t)3 * 262144;
    const bf16* bias = (const bf16*)(bb + 3 * 512);

    __shared__ short As[2][128 * 64];
    __shared__ short Bs[2][128 * 64];

    const int tid  = threadIdx.x;
    const int wave = tid >> 6, lane = tid & 63;
    const int wm = wave >> 1, wn = wave & 1;
    const int lm = lane & 15, quad = lane >> 4;
    const int srow = lane >> 3;
    const int scol = (lane & 7) * 8;

    floatx4 acc[4][4];
    const floatx4 zero = {0.f, 0.f, 0.f, 0.f};
    #pragma unroll
    for (int mt = 0; mt < 4; ++mt)
        #pragma unroll
        for (int nt = 0; nt < 4; ++nt) acc[mt][nt] = zero;

    auto stage = [&](int buf, int kt) {
        #pragma unroll
        for (int j = 0; j < 4; ++j) {
            const int issue = wave * 4 + j;          // 0..15, 8 rows each
            const int row = issue * 8 + srow;
            gload_lds16(A + (size_t)(mbase + row) * EMB + kt + scol,
                        &As[buf][issue * 512]);
            gload_lds16(W + (size_t)(nbase + row) * EMB + kt + scol,
                        &Bs[buf][issue * 512]);
        }
    };

    stage(0, 0);
    __syncthreads();

    #pragma unroll 2
    for (int step = 0; step < 8; ++step) {
        const int cur = step & 1;
        if (step < 7) stage(cur ^ 1, (step + 1) * 64);
        #pragma unroll
        for (int ks = 0; ks < 2; ++ks) {
            short8 af[4], bfr[4];
            #pragma unroll
            for (int mt = 0; mt < 4; ++mt)
                af[mt] = *reinterpret_cast<const short8*>(
                    &As[cur][(wm * 64 + mt * 16 + lm) * 64 + ks * 32 + quad * 8]);
            #pragma unroll
            for (int nt = 0; nt < 4; ++nt)
                bfr[nt] = *reinterpret_cast<const short8*>(
                    &Bs[cur][(wn * 64 + nt * 16 + lm) * 64 + ks * 32 + quad * 8]);
            #pragma unroll
            for (int mt = 0; mt < 4; ++mt)
                #pragma unroll
                for (int nt = 0; nt < 4; ++nt)
                    acc[mt][nt] = __builtin_amdgcn_mfma_f32_16x16x32_bf16(
                        af[mt], bfr[nt], acc[mt][nt], 0, 0, 0);
        }
        if (step < 7) __syncthreads();
    }

    #pragma unroll
    for (int nt = 0; nt < 4; ++nt) {
        const int col = nbase + wn * 64 + nt * 16 + lm;
        const float bv_ = load_elem(bias, col);
        #pragma unroll
        for (int mt = 0; mt < 4; ++mt)
            #pragma unroll
            for (int r = 0; r < 4; ++r) {
                const int row = mbase + wm * 64 + mt * 16 + quad * 4 + r;
                const float v = acc[mt][nt][r] + bv_;
                if (mode) ((float*)out)[(size_t)row * EMB + col] = v;
                else      ((bf16*)out)[(size_t)row * EMB + col] = __float2bfloat16(v);
            }
    }
}

// ---------------------------------------------------------------------------
extern "C" void kernel_launch(void* const* d_in, const int* in_sizes, int n_in,
                              void* d_out, int out_size, void* d_ws, size_t ws_size,
                              hipStream_t stream)
{
    // workspace (~58.3 MB of the 256 MB ws):
    //   reserved 64 B
    //   Qf/Kf/Vf : bf16 4,194,304 each                (24 MB)
    //   union  : [ KVt fp32 4,194,304 | xb bf16 4,194,304 ]  (16 MB)
    //   ksum   : fp32 65,536                           (0.25 MB)
    //   Of     : bf16 4,194,304                        (8 MB)
    //   Wb     : bf16 4x262,144                        (2 MB)
    //   bb     : bf16 4x512                            (4 KB)
    //   KVb    : bf16 4,194,304 (prefixed state)       (8 MB)
    bf16* Qf = (bf16*)((char*)d_ws + 64);
    bf16* Kf = Qf + 4194304;
    bf16* Vf = Kf + 4194304;
    float* KVt = (float*)(Vf + 4194304);
    short* xb = (short*)KVt;                // aliased (disjoint lifetime)
    float* ks = KVt + 4194304;
    bf16* Of = (bf16*)(ks + 65536);
    short* Wb = (short*)(Of + 4194304);
    short* bb = Wb + 1048576;
    bf16* KVb = (bf16*)(bb + 2048);

    convert_all<<<dim3(2561), 256, 0, stream>>>(
        d_in[0], d_in[1], d_in[2], d_in[3], d_in[4],
        d_in[5], d_in[6], d_in[7], d_in[8], xb, Wb, bb);

    qkv_gemm_dl<<<dim3(32, 8), 512, 0, stream>>>(xb, Wb, bb, Qf, Kf, Vf);
    chunk_kv<<<dim3(BHEADS * NCHUNK), 256, 0, stream>>>(Kf, Vf, KVt, ks);
    prefix_kv<<<dim3(BHEADS * 16), 256, 0, stream>>>(KVt, KVb, ks);
    attn_mfma<<<dim3(BHEADS * NCHUNK), 256, 0, stream>>>(Qf, Kf, Vf, KVb, ks, Of);

    out_proj_dl<<<dim3(64, 4), 256, 0, stream>>>(
        d_in[0], (const short*)Of, Wb, bb, d_out);
}

// Round 5
// 153.309 us; speedup vs baseline: 1.0090x; 1.0090x over previous
//
#include <hip/hip_runtime.h>
#include <hip/hip_bf16.h>

// Problem constants: B=2, T=4096, E=512, H=8, D=64
#define T_SEQ 4096
#define EMB   512
#define NH    8
#define HD    64
#define BATCH 2
#define M_ROWS (BATCH * T_SEQ)   // 8192
#define NCHUNK 64                // T / CS
#define CS     64                // chunk size
#define BHEADS (BATCH * NH)      // 16

using bf16 = __hip_bfloat16;
typedef __attribute__((ext_vector_type(8))) short short8;   // 8 bf16 = 4 VGPR
typedef __attribute__((ext_vector_type(4))) float floatx4;  // MFMA acc

__device__ __forceinline__ float bs2f(short s) {
    return __uint_as_float(((unsigned)(unsigned short)s) << 16);
}
__device__ __forceinline__ short f2bs(float f) {
    bf16 h = __float2bfloat16(f);
    return *reinterpret_cast<short*>(&h);
}
__device__ __forceinline__ float load_elem(const bf16* p, size_t i) {
    return __bfloat162float(p[i]);
}
// convert 8 consecutive elems (any dtype) -> bf16, 16B write
__device__ __forceinline__ void stage8(const bf16* g, short* l) {
    *reinterpret_cast<short8*>(l) = *reinterpret_cast<const short8*>(g);
}
__device__ __forceinline__ void stage8(const float* g, short* l) {
    float4 a = *reinterpret_cast<const float4*>(g);
    float4 b = *reinterpret_cast<const float4*>(g + 4);
    short8 v;
    v[0] = f2bs(a.x); v[1] = f2bs(a.y); v[2] = f2bs(a.z); v[3] = f2bs(a.w);
    v[4] = f2bs(b.x); v[5] = f2bs(b.y); v[6] = f2bs(b.z); v[7] = f2bs(b.w);
    *reinterpret_cast<short8*>(l) = v;
}

// async global->LDS: each lane copies 16B to (wave-uniform base) + lane*16
__device__ __forceinline__ void gload_lds16(const short* g, short* l) {
    __builtin_amdgcn_global_load_lds(
        (const __attribute__((address_space(1))) void*)g,
        (__attribute__((address_space(3))) void*)l, 16, 0, 0);
}

#define LDSTR 72   // padded LDS row stride (shorts) for transposed tiles

// ---------------------------------------------------------------------------
// In-block dtype probe (validated).  Requires 256+ threads; uses tid&255.
// ---------------------------------------------------------------------------
__device__ __forceinline__ int probe_mode(const void* x) {
    const uint4* p = (const uint4*)x;
    const int tid = threadIdx.x & 255;
    bool bad = false;
    #pragma unroll
    for (int i = 0; i < 2; ++i) {
        uint4 u = p[tid + i * 256];
        const unsigned w[4] = {u.x, u.y, u.z, u.w};
        #pragma unroll
        for (int k = 0; k < 4; ++k) {
            const float f = __uint_as_float(w[k] << 16);   // low half (even short)
            if (!(fabsf(f) <= 1e9f)) bad = true;
        }
    }
    return __syncthreads_or(bad ? 1 : 0) ? 1 : 0;
}

// ---------------------------------------------------------------------------
// Kernel 1: convert x, Wq/Wk/Wv/Wo, biases -> bf16 workspace (self-probing).
// ---------------------------------------------------------------------------
template <typename T>
__device__ __forceinline__ void convert_body(
    const void* const* in, short* xb, short* Wb, short* bb, int c)
{
    if (c < 524288) {
        stage8((const T*)in[0] + (size_t)c * 8, xb + (size_t)c * 8);
    } else if (c < 655360) {
        const int c2 = c - 524288;
        const int w = c2 >> 15;             // 0..3 : Wq Wk Wv Wo
        const int off = (c2 & 32767) * 8;
        const T* src = (const T*)in[w == 0 ? 1 : (w == 1 ? 3 : (w == 2 ? 5 : 7))];
        stage8(src + off, Wb + w * 262144 + off);
    } else if (c < 655616) {
        const int c3 = c - 655360;          // 0..255
        const int bsel = c3 >> 6;
        const int off = (c3 & 63) * 8;
        const T* src = (const T*)in[bsel == 0 ? 2 : (bsel == 1 ? 4 : (bsel == 2 ? 6 : 8))];
        stage8(src + off, bb + bsel * 512 + off);
    }
}

__global__ __launch_bounds__(256) void convert_all(
    const void* x, const void* Wq, const void* bq,
    const void* Wk, const void* bk, const void* Wv, const void* bv,
    const void* Wo, const void* bo,
    short* __restrict__ xb, short* __restrict__ Wb, short* __restrict__ bb)
{
    const void* in[9] = {x, Wq, bq, Wk, bk, Wv, bv, Wo, bo};
    const int mode = probe_mode(x);
    const int c = blockIdx.x * 256 + threadIdx.x;
    if (mode) convert_body<float>(in, xb, Wb, bb, c);
    else      convert_body<bf16>(in, xb, Wb, bb, c);
}

// ---------------------------------------------------------------------------
// Kernel 2: fused QKV projection — 256x192 tile, BK=32, TRIPLE buffer with
// COUNTED vmcnt (T4) + raw s_barrier (loads stay in flight across barriers;
// never vmcnt(0) mid-loop) and T2 XOR-swizzled LDS (pre-swizzled global
// source col, linear gload_lds dest, same swizzle on ds_read — rule #21).
// Grid (32,8) = 256 blocks = exactly 1/CU.  LDS 84KB.  512 threads.
//
// Swizzle (BK=32, 64B rows = 4 x 16B slots): slot = cb ^ ((row>>1)&3)
//   -> a wave's 64-lane fragment read (16 rows x 4 quads) touches each
//      16B-slot-position exactly twice = 2-way = free (m136).
// vmcnt accounting: per wave per stage: A 2 issues + B 2 (waves 0-3) or
// 1 (waves 4-7).  Uniform vmcnt(3): drains everything except (part of)
// the newest stage -> buffer k+1 guaranteed complete at the barrier.
// ---------------------------------------------------------------------------
__global__ __launch_bounds__(512) void qkv_gemm_dl(
    const short* __restrict__ xb, const short* __restrict__ Wb,
    const short* __restrict__ bb,
    bf16* __restrict__ Qf, bf16* __restrict__ Kf, bf16* __restrict__ Vf)
{
    const int mbase = blockIdx.x * 256;      // 0..31
    const int nbase = blockIdx.y * 192;      // 0..7 -> cols 0..1535

    __shared__ short As[3][16 * 512];   // 16KB x3: 256 rows x 32 cols
    __shared__ short Bs[3][12 * 512];   // 12KB x3: 192 rows x 32 cols

    const int tid  = threadIdx.x;
    const int wave = tid >> 6, lane = tid & 63;   // 8 waves
    const int wm = wave >> 1, wn = wave & 1;      // 4M x 2N over 256x192
    const int lm = lane & 15, quad = lane >> 4;
    // staging geometry (BK=32): issue = 16 rows x 32 cols; lane covers
    // row = issue*16 + (lane>>2), LINEAR slot cb = lane&3.  Pre-swizzled
    // global colblock g = cb ^ ((row>>1)&3) = (lane&3) ^ ((lane>>3)&3).
    const int srow = lane >> 2;                     // 0..15
    const int gcol = (((lane & 3) ^ ((lane >> 3) & 3))) * 8;  // 0,8,16,24
    // fragment-read swizzle term (row-base bits vanish mod 4 after >>1)
    const int rsw = ((lm >> 1) & 3);

    floatx4 acc[4][6];
    const floatx4 zero = {0.f, 0.f, 0.f, 0.f};
    #pragma unroll
    for (int mt = 0; mt < 4; ++mt)
        #pragma unroll
        for (int nt = 0; nt < 6; ++nt) acc[mt][nt] = zero;

    // stage one K-step (32 cols) of A(256 rows) + B(192 rows) into buffer buf
    auto stage = [&](int buf, int step) {
        const int kt = step * 32;
        #pragma unroll
        for (int j = 0; j < 2; ++j) {                 // A: 16 issues, 2/wave
            const int issue = wave * 2 + j;           // 0..15
            const int row = issue * 16 + srow;        // 0..255
            gload_lds16(xb + (size_t)(mbase + row) * EMB + kt + gcol,
                        &As[buf][issue * 512]);
        }
        if (wave < 4) {                               // B: 12 issues
            #pragma unroll
            for (int j = 0; j < 2; ++j) {
                const int issue = wave * 2 + j;       // 0..7
                const int row = issue * 16 + srow;    // 0..127
                gload_lds16(Wb + (size_t)(nbase + row) * EMB + kt + gcol,
                            &Bs[buf][issue * 512]);
            }
        } else {
            const int issue = 8 + (wave - 4);         // 8..11
            const int row = issue * 16 + srow;        // 128..191
            gload_lds16(Wb + (size_t)(nbase + row) * EMB + kt + gcol,
                        &Bs[buf][issue * 512]);
        }
    };

    stage(0, 0);
    stage(1, 1);
    asm volatile("s_waitcnt vmcnt(3)" ::: "memory");   // buffer 0 complete
    __builtin_amdgcn_sched_barrier(0);
    __builtin_amdgcn_s_barrier();

    #pragma unroll
    for (int step = 0; step < 16; ++step) {
        const int cur = step % 3;
        if (step + 2 < 16) stage((step + 2) % 3, step + 2);  // depth-2 prefetch

        short8 af[4], bfr[6];
        #pragma unroll
        for (int mt = 0; mt < 4; ++mt)
            af[mt] = *reinterpret_cast<const short8*>(
                &As[cur][(wm * 64 + mt * 16 + lm) * 32 + (quad ^ rsw) * 8]);
        #pragma unroll
        for (int nt = 0; nt < 6; ++nt)
            bfr[nt] = *reinterpret_cast<const short8*>(
                &Bs[cur][(wn * 96 + nt * 16 + lm) * 32 + (quad ^ rsw) * 8]);
        #pragma unroll
        for (int mt = 0; mt < 4; ++mt)
            #pragma unroll
            for (int nt = 0; nt < 6; ++nt)
                acc[mt][nt] = __builtin_amdgcn_mfma_f32_16x16x32_bf16(
                    af[mt], bfr[nt], acc[mt][nt], 0, 0, 0);

        if (step < 15) {
            if (step + 2 < 16) {
                asm volatile("s_waitcnt vmcnt(3)" ::: "memory");  // k+1 done,
            } else {                                              // k+2 in flight
                asm volatile("s_waitcnt vmcnt(0)" ::: "memory");  // tail drain
            }
            __builtin_amdgcn_sched_barrier(0);
            __builtin_amdgcn_s_barrier();
        }
    }

    #pragma unroll
    for (int nt = 0; nt < 6; ++nt) {
        const int col = nbase + wn * 96 + nt * 16 + lm;   // 0..1535
        const int which = col >> 9;                        // 0=Q 1=K 2=V
        const int cw = col & 511;
        const float bv_ = load_elem((const bf16*)bb, col); // bb: Q/K/V first
        const int h = cw >> 6, d = cw & 63;
        bf16* outp = (which == 0) ? Qf : ((which == 1) ? Kf : Vf);
        #pragma unroll
        for (int mt = 0; mt < 4; ++mt)
            #pragma unroll
            for (int r = 0; r < 4; ++r) {
                const int row = mbase + wm * 64 + mt * 16 + quad * 4 + r;
                const int b = row >> 12, t = row & (T_SEQ - 1);
                float v = acc[mt][nt][r] + bv_;
                if (which != 2) v = (v > 0.f) ? (v + 1.f) : __expf(v);  // elu+1
                outp[(((size_t)(b * NH + h)) * T_SEQ + t) * HD + d] = __float2bfloat16(v);
            }
    }
}

// ---------------------------------------------------------------------------
// Kernel 3: per-chunk (K^T V)^T via MFMA + k column sums.  1024 blocks.
// ---------------------------------------------------------------------------
__global__ __launch_bounds__(256) void chunk_kv(
    const bf16* __restrict__ Kf, const bf16* __restrict__ Vf,
    float* __restrict__ KVt, float* __restrict__ ksum)
{
    const int bh = blockIdx.x >> 6;
    const int c  = blockIdx.x & 63;
    __shared__ short Kt[64 * LDSTR];   // Kt[dk][s]
    __shared__ short Vt[64 * LDSTR];   // Vt[dv][s]
    const int tid = threadIdx.x;
    const bf16* kp = Kf + ((size_t)bh * T_SEQ + c * CS) * HD;
    const bf16* vp = Vf + ((size_t)bh * T_SEQ + c * CS) * HD;

    #pragma unroll
    for (int j = 0; j < 2; ++j) {
        const int u = j * 256 + tid;
        const int e0 = u * 8;
        const int s = e0 >> 6, d0 = e0 & 63;
        short8 ku = *reinterpret_cast<const short8*>(kp + e0);
        short8 vu = *reinterpret_cast<const short8*>(vp + e0);
        #pragma unroll
        for (int i = 0; i < 8; ++i) {
            Kt[(d0 + i) * LDSTR + s] = ku[i];
            Vt[(d0 + i) * LDSTR + s] = vu[i];
        }
    }
    __syncthreads();

    const int w = tid >> 6, lane = tid & 63;
    const int lm = lane & 15, quad = lane >> 4;

    floatx4 acc[4];
    const floatx4 zero = {0.f, 0.f, 0.f, 0.f};
    #pragma unroll
    for (int nt = 0; nt < 4; ++nt) acc[nt] = zero;

    #pragma unroll
    for (int ks = 0; ks < 2; ++ks) {
        short8 av = *reinterpret_cast<const short8*>(
            &Vt[(w * 16 + lm) * LDSTR + ks * 32 + quad * 8]);   // A: rows = dv
        #pragma unroll
        for (int nt = 0; nt < 4; ++nt) {
            short8 bk = *reinterpret_cast<const short8*>(
                &Kt[(nt * 16 + lm) * LDSTR + ks * 32 + quad * 8]);  // B: cols = dk
            acc[nt] = __builtin_amdgcn_mfma_f32_16x16x32_bf16(av, bk, acc[nt], 0, 0, 0);
        }
    }

    float* kvout = KVt + ((size_t)bh * NCHUNK + c) * 4096;
    #pragma unroll
    for (int nt = 0; nt < 4; ++nt)
        #pragma unroll
        for (int r = 0; r < 4; ++r)
            kvout[(w * 16 + quad * 4 + r) * 64 + nt * 16 + lm] = acc[nt][r];

    if (tid < 64) {
        float s = 0.f;
        #pragma unroll 8
        for (int t = 0; t < 64; ++t) s += bs2f(Kt[tid * LDSTR + t]);
        ksum[((size_t)bh * NCHUNK + c) * 64 + tid] = s;
    }
}

// ---------------------------------------------------------------------------
// Kernel 4: exclusive prefix over chunks — element-parallel.  fp32 scan
// internally, bf16 output (attn rounds to bf16 anyway -> bit-identical).
// ---------------------------------------------------------------------------
__global__ __launch_bounds__(256) void prefix_kv(
    const float* __restrict__ KVt, bf16* __restrict__ KVb,
    float* __restrict__ ksum)
{
    const int bh   = blockIdx.x >> 4;
    const int part = blockIdx.x & 15;
    const int tid  = threadIdx.x;
    const int e    = part * 256 + tid;
    const float* src = KVt + (size_t)bh * NCHUNK * 4096 + e;
    bf16* dst = KVb + (size_t)bh * NCHUNK * 4096 + e;

    float s = 0.f;
    #pragma unroll
    for (int cb = 0; cb < 2; ++cb) {
        float v[32];
        #pragma unroll
        for (int i = 0; i < 32; ++i) v[i] = src[(size_t)(cb * 32 + i) * 4096];
        #pragma unroll
        for (int i = 0; i < 32; ++i) {
            dst[(size_t)(cb * 32 + i) * 4096] = __float2bfloat16(s);
            s += v[i];
        }
    }

    if (part == 0 && tid < 64) {
        float* zb = ksum + (size_t)bh * NCHUNK * 64 + tid;
        float z = 0.f;
        #pragma unroll
        for (int cb = 0; cb < 4; ++cb) {
            float zv[16];
            #pragma unroll
            for (int i = 0; i < 16; ++i) zv[i] = zb[(size_t)(cb * 16 + i) * 64];
            #pragma unroll
            for (int i = 0; i < 16; ++i) {
                zb[(size_t)(cb * 16 + i) * 64] = z;
                z += zv[i];
            }
        }
    }
}

// ---------------------------------------------------------------------------
// Kernel 5: per-chunk attention, all-MFMA, registerized denominator.
// 4 blocks/CU (37.25KB LDS), single occupancy wave.
// ---------------------------------------------------------------------------
__global__ __launch_bounds__(256, 4) void attn_mfma(
    const bf16* __restrict__ Qf, const bf16* __restrict__ Kf,
    const bf16* __restrict__ Vf, const bf16* __restrict__ KVb,
    const float* __restrict__ ksum, bf16* __restrict__ Of)
{
    const int bh = blockIdx.x >> 6;
    const int c  = blockIdx.x & 63;
    const int b  = bh >> 3, h = bh & 7;

    __shared__ short Qs [64 * LDSTR];
    __shared__ short Ksn[64 * LDSTR];
    __shared__ short Vt [64 * LDSTR];
    __shared__ short Ps [64 * LDSTR];
    __shared__ float zprev[64];

    const int tid = threadIdx.x;
    const int w = tid >> 6, lane = tid & 63;
    const int lm = lane & 15, quad = lane >> 4;
    const size_t coff = ((size_t)bh * T_SEQ + c * CS) * HD;
    const bf16* Sb = KVb + ((size_t)bh * NCHUNK + c) * 4096;

    #pragma unroll
    for (int j = 0; j < 2; ++j) {
        const int u  = j * 256 + tid;
        const int e0 = u * 8;
        const int r = e0 >> 6, cc = e0 & 63;
        *reinterpret_cast<short8*>(&Qs [r * LDSTR + cc]) =
            *reinterpret_cast<const short8*>(Qf + coff + e0);
        *reinterpret_cast<short8*>(&Ksn[r * LDSTR + cc]) =
            *reinterpret_cast<const short8*>(Kf + coff + e0);
        short8 vu = *reinterpret_cast<const short8*>(Vf + coff + e0);
        #pragma unroll
        for (int i = 0; i < 8; ++i) Vt[(cc + i) * LDSTR + r] = vu[i];
    }
    if (tid < 64) zprev[tid] = ksum[((size_t)bh * NCHUNK + c) * 64 + tid];
    __syncthreads();

    const floatx4 zero = {0.f, 0.f, 0.f, 0.f};
    short8 aq[2];
    #pragma unroll
    for (int ks = 0; ks < 2; ++ks)
        aq[ks] = *reinterpret_cast<const short8*>(
            &Qs[(w * 16 + lm) * LDSTR + ks * 32 + quad * 8]);

    floatx4 pacc[4];
    #pragma unroll
    for (int nt = 0; nt < 4; ++nt) pacc[nt] = zero;
    #pragma unroll
    for (int ks = 0; ks < 2; ++ks)
        #pragma unroll
        for (int nt = 0; nt < 4; ++nt) {
            short8 bk = *reinterpret_cast<const short8*>(
                &Ksn[(nt * 16 + lm) * LDSTR + ks * 32 + quad * 8]);
            pacc[nt] = __builtin_amdgcn_mfma_f32_16x16x32_bf16(aq[ks], bk, pacc[nt], 0, 0, 0);
        }

    float tot[4] = {0.f, 0.f, 0.f, 0.f};
    #pragma unroll
    for (int nt = 0; nt < 4; ++nt)
        #pragma unroll
        for (int r = 0; r < 4; ++r) {
            const int t = w * 16 + quad * 4 + r;
            const int s = nt * 16 + lm;
            const float m = (s <= t) ? pacc[nt][r] : 0.f;
            Ps[t * LDSTR + s] = f2bs(m);
            tot[r] += m;
        }
    #pragma unroll
    for (int r = 0; r < 4; ++r) {
        const int t = w * 16 + quad * 4 + r;
        #pragma unroll
        for (int j = 0; j < 4; ++j) {
            const int d = lm + j * 16;
            tot[r] += bs2f(Qs[t * LDSTR + d]) * zprev[d];
        }
    }
    #pragma unroll
    for (int mask = 1; mask < 16; mask <<= 1)
        #pragma unroll
        for (int r = 0; r < 4; ++r) tot[r] += __shfl_xor(tot[r], mask);
    float rdenl[4];
    #pragma unroll
    for (int r = 0; r < 4; ++r) rdenl[r] = 1.f / (tot[r] + 1e-6f);

    floatx4 oacc[4];
    #pragma unroll
    for (int nt = 0; nt < 4; ++nt) oacc[nt] = zero;
    #pragma unroll
    for (int ks = 0; ks < 2; ++ks)
        #pragma unroll
        for (int nt = 0; nt < 4; ++nt) {
            short8 bs = *reinterpret_cast<const short8*>(
                Sb + (nt * 16 + lm) * 64 + ks * 32 + quad * 8);
            oacc[nt] = __builtin_amdgcn_mfma_f32_16x16x32_bf16(aq[ks], bs, oacc[nt], 0, 0, 0);
        }

    #pragma unroll
    for (int ks = 0; ks < 2; ++ks) {
        short8 ap = *reinterpret_cast<const short8*>(
            &Ps[(w * 16 + lm) * LDSTR + ks * 32 + quad * 8]);
        #pragma unroll
        for (int nt = 0; nt < 4; ++nt) {
            short8 bv = *reinterpret_cast<const short8*>(
                &Vt[(nt * 16 + lm) * LDSTR + ks * 32 + quad * 8]);
            oacc[nt] = __builtin_amdgcn_mfma_f32_16x16x32_bf16(ap, bv, oacc[nt], 0, 0, 0);
        }
    }

    #pragma unroll
    for (int nt = 0; nt < 4; ++nt)
        #pragma unroll
        for (int r = 0; r < 4; ++r) {
            const int t  = w * 16 + quad * 4 + r;
            const int dv = nt * 16 + lm;
            const int tg = c * CS + t;
            Of[((size_t)(b * T_SEQ + tg)) * EMB + h * HD + dv] =
                __float2bfloat16(oacc[nt][r] * rdenl[r]);
        }
}

// ---------------------------------------------------------------------------
// Kernel 6: output projection — 128x128 tile, double-buffer (r4, neutral but
// harmless).  Grid (64,4) = 256 blocks = 1/CU.  LDS 64KB.
// ---------------------------------------------------------------------------
__global__ __launch_bounds__(256) void out_proj_dl(
    const void* __restrict__ xprobe,
    const short* __restrict__ A, const short* __restrict__ Wb,
    const short* __restrict__ bb, void* __restrict__ out)
{
    const int mode = probe_mode(xprobe);

    const int mbase = blockIdx.x * 128;
    const int nbase = blockIdx.y * 128;
    const short* W = Wb + (size_t)3 * 262144;
    const bf16* bias = (const bf16*)(bb + 3 * 512);

    __shared__ short As[2][128 * 64];
    __shared__ short Bs[2][128 * 64];

    const int tid  = threadIdx.x;
    const int wave = tid >> 6, lane = tid & 63;
    const int wm = wave >> 1, wn = wave & 1;
    const int lm = lane & 15, quad = lane >> 4;
    const int srow = lane >> 3;
    const int scol = (lane & 7) * 8;

    floatx4 acc[4][4];
    const floatx4 zero = {0.f, 0.f, 0.f, 0.f};
    #pragma unroll
    for (int mt = 0; mt < 4; ++mt)
        #pragma unroll
        for (int nt = 0; nt < 4; ++nt) acc[mt][nt] = zero;

    auto stage = [&](int buf, int kt) {
        #pragma unroll
        for (int j = 0; j < 4; ++j) {
            const int issue = wave * 4 + j;          // 0..15, 8 rows each
            const int row = issue * 8 + srow;
            gload_lds16(A + (size_t)(mbase + row) * EMB + kt + scol,
                        &As[buf][issue * 512]);
            gload_lds16(W + (size_t)(nbase + row) * EMB + kt + scol,
                        &Bs[buf][issue * 512]);
        }
    };

    stage(0, 0);
    __syncthreads();

    #pragma unroll 2
    for (int step = 0; step < 8; ++step) {
        const int cur = step & 1;
        if (step < 7) stage(cur ^ 1, (step + 1) * 64);
        #pragma unroll
        for (int ks = 0; ks < 2; ++ks) {
            short8 af[4], bfr[4];
            #pragma unroll
            for (int mt = 0; mt < 4; ++mt)
                af[mt] = *reinterpret_cast<const short8*>(
                    &As[cur][(wm * 64 + mt * 16 + lm) * 64 + ks * 32 + quad * 8]);
            #pragma unroll
            for (int nt = 0; nt < 4; ++nt)
                bfr[nt] = *reinterpret_cast<const short8*>(
                    &Bs[cur][(wn * 64 + nt * 16 + lm) * 64 + ks * 32 + quad * 8]);
            #pragma unroll
            for (int mt = 0; mt < 4; ++mt)
                #pragma unroll
                for (int nt = 0; nt < 4; ++nt)
                    acc[mt][nt] = __builtin_amdgcn_mfma_f32_16x16x32_bf16(
                        af[mt], bfr[nt], acc[mt][nt], 0, 0, 0);
        }
        if (step < 7) __syncthreads();
    }

    #pragma unroll
    for (int nt = 0; nt < 4; ++nt) {
        const int col = nbase + wn * 64 + nt * 16 + lm;
        const float bv_ = load_elem(bias, col);
        #pragma unroll
        for (int mt = 0; mt < 4; ++mt)
            #pragma unroll
            for (int r = 0; r < 4; ++r) {
                const int row = mbase + wm * 64 + mt * 16 + quad * 4 + r;
                const float v = acc[mt][nt][r] + bv_;
                if (mode) ((float*)out)[(size_t)row * EMB + col] = v;
                else      ((bf16*)out)[(size_t)row * EMB + col] = __float2bfloat16(v);
            }
    }
}

// ---------------------------------------------------------------------------
extern "C" void kernel_launch(void* const* d_in, const int* in_sizes, int n_in,
                              void* d_out, int out_size, void* d_ws, size_t ws_size,
                              hipStream_t stream)
{
    // workspace (~58.3 MB of the 256 MB ws):
    //   reserved 64 B
    //   Qf/Kf/Vf : bf16 4,194,304 each                (24 MB)
    //   union  : [ KVt fp32 4,194,304 | xb bf16 4,194,304 ]  (16 MB)
    //   ksum   : fp32 65,536                           (0.25 MB)
    //   Of     : bf16 4,194,304                        (8 MB)
    //   Wb     : bf16 4x262,144                        (2 MB)
    //   bb     : bf16 4x512                            (4 KB)
    //   KVb    : bf16 4,194,304 (prefixed state)       (8 MB)
    bf16* Qf = (bf16*)((char*)d_ws + 64);
    bf16* Kf = Qf + 4194304;
    bf16* Vf = Kf + 4194304;
    float* KVt = (float*)(Vf + 4194304);
    short* xb = (short*)KVt;                // aliased (disjoint lifetime)
    float* ks = KVt + 4194304;
    bf16* Of = (bf16*)(ks + 65536);
    short* Wb = (short*)(Of + 4194304);
    short* bb = Wb + 1048576;
    bf16* KVb = (bf16*)(bb + 2048);

    convert_all<<<dim3(2561), 256, 0, stream>>>(
        d_in[0], d_in[1], d_in[2], d_in[3], d_in[4],
        d_in[5], d_in[6], d_in[7], d_in[8], xb, Wb, bb);

    qkv_gemm_dl<<<dim3(32, 8), 512, 0, stream>>>(xb, Wb, bb, Qf, Kf, Vf);
    chunk_kv<<<dim3(BHEADS * NCHUNK), 256, 0, stream>>>(Kf, Vf, KVt, ks);
    prefix_kv<<<dim3(BHEADS * 16), 256, 0, stream>>>(KVt, KVb, ks);
    attn_mfma<<<dim3(BHEADS * NCHUNK), 256, 0, stream>>>(Qf, Kf, Vf, KVb, ks, Of);

    out_proj_dl<<<dim3(64, 4), 256, 0, stream>>>(
        d_in[0], (const short*)Of, Wb, bb, d_out);
}